// Round 11
// baseline (491.549 us; speedup 1.0000x reference)
//
#include <hip/hip_runtime.h>
#include <stdint.h>
#include <math.h>

typedef __attribute__((ext_vector_type(4))) int i32x4;
typedef __attribute__((ext_vector_type(16))) int i32x16;
typedef __attribute__((ext_vector_type(4))) float f32x4;

constexpr int D_DIM = 1280;   // embedding dim (lin1 K, lin2 N)
constexpr int H_DIM = 5120;   // mlp dim      (lin1 N, lin2 K)

__device__ __forceinline__ void gload_lds16(const void* g, void* l) {
  __builtin_amdgcn_global_load_lds(
      (const __attribute__((address_space(1))) void*)g,
      (__attribute__((address_space(3))) void*)l,
      16, 0, 0);
}

// ---- pack int32 (sign-extended int8) -> int8 --------------------------------
__global__ void __launch_bounds__(256) k_packw(const int* __restrict__ s1,
                                               const int* __restrict__ s2,
                                               int8_t* __restrict__ out,
                                               long wn) {
  long i = ((long)blockIdx.x * 256 + threadIdx.x) * 16;
  const int* p = (i < wn) ? (s1 + i) : (s2 + (i - wn));
  i32x4 a = *(const i32x4*)(p);
  i32x4 b = *(const i32x4*)(p + 4);
  i32x4 c = *(const i32x4*)(p + 8);
  i32x4 d = *(const i32x4*)(p + 12);
  i32x4 r;
  r.x = (a.x & 255) | ((a.y & 255) << 8) | ((a.z & 255) << 16) | (a.w << 24);
  r.y = (b.x & 255) | ((b.y & 255) << 8) | ((b.z & 255) << 16) | (b.w << 24);
  r.z = (c.x & 255) | ((c.y & 255) << 8) | ((c.z & 255) << 16) | (c.w << 24);
  r.w = (d.x & 255) | ((d.y & 255) << 8) | ((d.z & 255) << 16) | (d.w << 24);
  *(i32x4*)(out + i) = r;
}

__global__ void __launch_bounds__(256) k_pack(const int* __restrict__ in,
                                              int8_t* __restrict__ out,
                                              long n) {
  long i = ((long)blockIdx.x * 256 + threadIdx.x) * 16;
  if (i >= n) return;
  const int* p = in + i;
  i32x4 a = *(const i32x4*)(p);
  i32x4 b = *(const i32x4*)(p + 4);
  i32x4 c = *(const i32x4*)(p + 8);
  i32x4 d = *(const i32x4*)(p + 12);
  i32x4 r;
  r.x = (a.x & 255) | ((a.y & 255) << 8) | ((a.z & 255) << 16) | (a.w << 24);
  r.y = (b.x & 255) | ((b.y & 255) << 8) | ((b.z & 255) << 16) | (b.w << 24);
  r.z = (c.x & 255) | ((c.y & 255) << 8) | ((c.z & 255) << 16) | (c.w << 24);
  r.w = (d.x & 255) | ((d.y & 255) << 8) | ((d.z & 255) << 16) | (d.w << 24);
  *(i32x4*)(out + i) = r;
}

// ---- fused int8 GEMM: 128x128 tile, BK=128, 32x32x32 MFMA -------------------
// A [Mt*128, KDIM] staged through LDS (2-phase dbuf, r6-verified schedule).
// W [NDIM, KDIM] weight fragments loaded DIRECTLY global->VGPR (L2-resident;
//   double reg buffer, landed by the tile barrier's vmcnt drain). LDS carries
//   only A: ~6 LDS-cyc/MFMA vs 12 with both operands staged.
// GELU=true : transposed acc (mfma(w,a)); sigmoid-GELU + requant -> packed
//             dwords -> pad-132 LDS transpose -> coalesced dwordx4 stores.
// GELU=false: fp32 out = acc*s1 + bias, coalesced f32 stores.
template <int KDIM, int NDIM, bool GELU>
__global__ void __launch_bounds__(256, 2)
k_gemm(const int8_t* __restrict__ A, const int8_t* __restrict__ W,
       const float* __restrict__ bias, const float* __restrict__ ps1,
       const float* __restrict__ ps2, void* __restrict__ Cout, int Mtiles) {
  constexpr int BM = 128, BN = 128, BKB = 128;
  constexpr int NT = KDIM / BKB;   // 10 (lin1) / 40 (lin2); both even
  constexpr int BNC = NDIM / BN;   // 40 / 10
  constexpr int G = BNC * 4;

  // [A buf0 16K][A buf1 16K]; epilogue reuses as 128x132 transpose tile
  __shared__ __align__(16) int8_t smem[32768];

  // ---- block mapping: bijective XCD chunk + 4-row grouping (r4-verified) ----
  const int nwg = Mtiles * BNC;
  int bm, bn;
  {
    const int bid = blockIdx.x;
    const int q = nwg >> 3, r = nwg & 7, x = bid & 7, l = bid >> 3;
    const int swz = (x < r ? x * (q + 1) : r * (q + 1) + (x - r) * q) + l;
    if ((Mtiles & 3) == 0) {
      const int g = swz / G, rr = swz % G;
      bn = rr >> 2;
      bm = g * 4 + (rr & 3);
    } else {
      bn = swz % BNC;
      bm = swz / BNC;
    }
  }

  const int tid = threadIdx.x;
  const int lane = tid & 63, wid = tid >> 6;
  const int wr = wid >> 1, wc = wid & 1;  // 2x2 waves, 64x64 out each
  const int r32 = lane & 31, hi5 = lane >> 5;

  // ---- A staging: linear LDS dest, inverse-swizzled global source -----------
  const int srow = tid >> 3;                       // 0..31
  const int soff = (((tid & 7) ^ (srow & 7)) << 4);
  const int8_t* Ath = A + (size_t)(bm * BM + srow) * KDIM + soff;
  const int dT = tid * 16;

  auto STAGE = [&](int boff, int tt) {   // 4 gload_lds per thread
    const int8_t* g = Ath + tt * BKB;
#pragma unroll
    for (int p = 0; p < 4; ++p)
      gload_lds16(g + (size_t)(p * 32) * KDIM, smem + boff + dT + p * 4096);
  };

  // ---- W fragments: direct global->reg (frag row = lane&31, k = hi5*16) -----
  const int8_t* W0 = W + (size_t)(bn * BN + wc * 64 + r32) * KDIM + (hi5 << 4);
  const int8_t* W1p = W0 + (size_t)32 * KDIM;
  i32x4 wfA[8], wfB[8];
  auto LOADW = [&](i32x4 (&wf)[8], int tt) {   // 8 dwordx4 per thread
    const int o = tt * BKB;
#pragma unroll
    for (int ks = 0; ks < 4; ++ks) {
      wf[2 * ks]     = *(const i32x4*)(W0 + o + ks * 32);
      wf[2 * ks + 1] = *(const i32x4*)(W1p + o + ks * 32);
    }
  };

  // ---- A fragment offsets (XOR-swizzled; conflict-free pair, r5-verified) ---
  const int fsw = (lane & 7) << 4;
  const int kq = hi5 << 4;
  int koff[4];
#pragma unroll
  for (int ks = 0; ks < 4; ++ks) koff[ks] = ((ks * 32 + kq) ^ fsw);
  const int rowA = (wr * 64 + r32) * BKB;

  i32x16 acc[2][2] = {};

  auto COMPUTE = [&](int boff, const i32x4 (&wf)[8]) {
    const int8_t* Ab = smem + boff + rowA;
#pragma unroll
    for (int ks = 0; ks < 4; ++ks) {
      i32x4 a0 = *(const i32x4*)(Ab + koff[ks]);
      i32x4 a1 = *(const i32x4*)(Ab + 4096 + koff[ks]);
      __builtin_amdgcn_s_setprio(1);
      if constexpr (GELU) {  // transposed: acc[n][m], D-row = h, D-col = token
        acc[0][0] = __builtin_amdgcn_mfma_i32_32x32x32_i8(wf[2*ks],   a0, acc[0][0], 0, 0, 0);
        acc[0][1] = __builtin_amdgcn_mfma_i32_32x32x32_i8(wf[2*ks],   a1, acc[0][1], 0, 0, 0);
        acc[1][0] = __builtin_amdgcn_mfma_i32_32x32x32_i8(wf[2*ks+1], a0, acc[1][0], 0, 0, 0);
        acc[1][1] = __builtin_amdgcn_mfma_i32_32x32x32_i8(wf[2*ks+1], a1, acc[1][1], 0, 0, 0);
      } else {               // normal: acc[m][n], D-row = token, D-col = d
        acc[0][0] = __builtin_amdgcn_mfma_i32_32x32x32_i8(a0, wf[2*ks],   acc[0][0], 0, 0, 0);
        acc[0][1] = __builtin_amdgcn_mfma_i32_32x32x32_i8(a0, wf[2*ks+1], acc[0][1], 0, 0, 0);
        acc[1][0] = __builtin_amdgcn_mfma_i32_32x32x32_i8(a1, wf[2*ks],   acc[1][0], 0, 0, 0);
        acc[1][1] = __builtin_amdgcn_mfma_i32_32x32x32_i8(a1, wf[2*ks+1], acc[1][1], 0, 0, 0);
      }
      __builtin_amdgcn_s_setprio(0);
    }
  };

  // ---- main loop: r6-verified 2-phase dbuf; barrier's vmcnt(0) drain covers
  //      both the gload_lds staging AND the wf register loads ----------------
  STAGE(0, 0);
  LOADW(wfA, 0);
  __syncthreads();
#pragma unroll 1
  for (int t = 0; t < NT; t += 2) {
    STAGE(16384, t + 1);             // tile t+1 A -> buf1
    LOADW(wfB, t + 1);               // tile t+1 W -> regs
    COMPUTE(0, wfA);                 // tile t
    __syncthreads();                 // buf1 + wfB landed; buf0 free
    if (t + 2 < NT) { STAGE(0, t + 2); LOADW(wfA, t + 2); }
    COMPUTE(16384, wfB);             // tile t+1
    __syncthreads();
  }

  // ---- epilogue -------------------------------------------------------------
  // 32x32 C/D layout: col = lane&31, row = (reg&3) + 8*(reg>>2) + 4*(lane>>5)
  if constexpr (GELU) {
    const float s1 = *ps1;
    const float rs = 1.0f / (*ps2);
    int8_t* Q = (int8_t*)Cout;
    // pad-132 transpose tile: 128 tok rows x (128 h + 4 pad) B; bank(tok,0)=tok
    int8_t* lb = smem;
#pragma unroll
    for (int n = 0; n < 2; ++n) {
#pragma unroll
      for (int q = 0; q < 4; ++q) {
        const int hl = wc * 64 + n * 32 + q * 8 + hi5 * 4;  // local h base
        const f32x4 bv = *(const f32x4*)(bias + bn * BN + hl);
#pragma unroll
        for (int m = 0; m < 2; ++m) {
          const int tok = wr * 64 + m * 32 + r32;           // local token
          uint32_t pk = 0;
#pragma unroll
          for (int rr = 0; rr < 4; ++rr) {
            const float h = __builtin_fmaf((float)acc[n][m][q * 4 + rr], s1, bv[rr]);
            // sigmoid-GELU: h * sigma(1.702h); exact in both saturation tails
            const float e = __expf(-1.702f * h);
            const float g = h * __builtin_amdgcn_rcpf(1.0f + e);
            float qf = rintf(g * rs);
            qf = fminf(127.0f, fmaxf(-128.0f, qf));
            pk |= ((uint32_t)((int)qf & 255)) << (rr * 8);
          }
          *(uint32_t*)(lb + tok * 132 + hl) = pk;
        }
      }
    }
    __syncthreads();
    // readback: 4-aligned b32 reads (free 2-way max), coalesced dwordx4 stores
#pragma unroll
    for (int it = 0; it < 4; ++it) {
      const int row = it * 32 + (tid >> 3);
      const int sl = tid & 7;
      const int8_t* rp = lb + row * 132 + sl * 16;
      i32x4 v;
      v.x = *(const int*)(rp);
      v.y = *(const int*)(rp + 4);
      v.z = *(const int*)(rp + 8);
      v.w = *(const int*)(rp + 12);
      *(i32x4*)(Q + (size_t)(bm * BM + row) * NDIM + bn * BN + sl * 16) = v;
    }
  } else {
    const float s1 = *ps1;
    float* O = (float*)Cout;
    const int colb = bn * BN + wc * 64 + r32;
#pragma unroll
    for (int n = 0; n < 2; ++n) {
      const int col = colb + n * 32;
      const float bv = bias[col];
#pragma unroll
      for (int m = 0; m < 2; ++m) {
        const int rowb = bm * BM + wr * 64 + m * 32 + hi5 * 4;
#pragma unroll
        for (int q = 0; q < 4; ++q)
#pragma unroll
          for (int rr = 0; rr < 4; ++rr) {
            const int row = rowb + q * 8 + rr;
            O[(size_t)row * NDIM + col] =
                __builtin_fmaf((float)acc[m][n][q * 4 + rr], s1, bv);
          }
      }
    }
  }
}

extern "C" void kernel_launch(void* const* d_in, const int* in_sizes, int n_in,
                              void* d_out, int out_size, void* d_ws, size_t ws_size,
                              hipStream_t stream) {
  (void)in_sizes; (void)n_in; (void)out_size;
  const int*   x32  = (const int*)d_in[0];
  const int*   w132 = (const int*)d_in[1];
  const float* b1   = (const float*)d_in[2];
  const int*   w232 = (const int*)d_in[3];
  const float* b2   = (const float*)d_in[4];
  const float* a1   = (const float*)d_in[5];
  const float* sreq = (const float*)d_in[6];
  const float* a2   = (const float*)d_in[7];
  float* out = (float*)d_out;

  const int M = 4 * 4096;                       // 16384 tokens
  const size_t WN = (size_t)H_DIM * D_DIM;      // 6,553,600 weights each
  constexpr int BM = 128, BN = 128;

  int8_t* w1p  = (int8_t*)d_ws;
  int8_t* w2p  = w1p + WN;
  int8_t* base = w2p + WN;

  // chunk M (multiple of 128) so packed-x chunk + q chunk fit in workspace
  size_t avail = ws_size > 2 * WN ? ws_size - 2 * WN : 0;
  size_t rows = avail / (size_t)(D_DIM + H_DIM);
  int Mc = (int)((rows / BM) * BM);
  if (Mc > M) Mc = M;
  if (Mc < BM) Mc = BM;

  k_packw<<<(int)(2 * WN / 4096), 256, 0, stream>>>(w132, w232, w1p, (long)WN);

  for (int m0 = 0; m0 < M; m0 += Mc) {
    const int mc = (M - m0 < Mc) ? (M - m0) : Mc;
    int8_t* xp = base;
    int8_t* q  = base + (size_t)Mc * D_DIM;
    const size_t nx = (size_t)mc * D_DIM;
    const int mt = mc / BM;
    k_pack<<<(int)(nx / 4096), 256, 0, stream>>>(x32 + (size_t)m0 * D_DIM, xp, (long)nx);
    k_gemm<D_DIM, H_DIM, true><<<mt * (H_DIM / BN), 256, 0, stream>>>(
        xp, w1p, b1, a1, sreq, q, mt);
    k_gemm<H_DIM, D_DIM, false><<<mt * (D_DIM / BN), 256, 0, stream>>>(
        q, w2p, b2, a2, nullptr, out + (size_t)m0 * D_DIM, mt);
  }
}

// Round 12
// 297.468 us; speedup vs baseline: 1.6524x; 1.6524x over previous
//
#include <hip/hip_runtime.h>
#include <stdint.h>
#include <math.h>

typedef __attribute__((ext_vector_type(4))) int i32x4;
typedef __attribute__((ext_vector_type(16))) int i32x16;
typedef __attribute__((ext_vector_type(4))) float f32x4;

constexpr int D_DIM = 1280;   // embedding dim (lin1 K, lin2 N)
constexpr int H_DIM = 5120;   // mlp dim      (lin1 N, lin2 K)

__device__ __forceinline__ void gload_lds16(const void* g, void* l) {
  __builtin_amdgcn_global_load_lds(
      (const __attribute__((address_space(1))) void*)g,
      (__attribute__((address_space(3))) void*)l,
      16, 0, 0);
}

__device__ __forceinline__ i32x4 pack16(const int* __restrict__ p) {
  i32x4 a = *(const i32x4*)(p);
  i32x4 b = *(const i32x4*)(p + 4);
  i32x4 c = *(const i32x4*)(p + 8);
  i32x4 d = *(const i32x4*)(p + 12);
  i32x4 r;
  r.x = (a.x & 255) | ((a.y & 255) << 8) | ((a.z & 255) << 16) | (a.w << 24);
  r.y = (b.x & 255) | ((b.y & 255) << 8) | ((b.z & 255) << 16) | (b.w << 24);
  r.z = (c.x & 255) | ((c.y & 255) << 8) | ((c.z & 255) << 16) | (c.w << 24);
  r.w = (d.x & 255) | ((d.y & 255) << 8) | ((d.z & 255) << 16) | (d.w << 24);
  return r;
}

// ---- fused pack: w1 | w2 | x in ONE launch (int32 sign-extended -> int8) ----
__global__ void __launch_bounds__(256) k_pack3(const int* __restrict__ s1,
                                               const int* __restrict__ s2,
                                               const int* __restrict__ s3,
                                               int8_t* __restrict__ out,
                                               long wn, long nx) {
  long i = ((long)blockIdx.x * 256 + threadIdx.x) * 16;
  if (i >= 2 * wn + nx) return;
  const int* p = (i < wn) ? (s1 + i)
               : (i < 2 * wn) ? (s2 + (i - wn)) : (s3 + (i - 2 * wn));
  *(i32x4*)(out + i) = pack16(p);
}

__global__ void __launch_bounds__(256) k_pack(const int* __restrict__ in,
                                              int8_t* __restrict__ out,
                                              long n) {
  long i = ((long)blockIdx.x * 256 + threadIdx.x) * 16;
  if (i >= n) return;
  *(i32x4*)(out + i) = pack16(in + i);
}

// ---- fused int8 GEMM: 128x128 tile, BK=128, 32x32x32 MFMA, static dbuf ------
// (r9-verified structure: simple 2-phase dbuf, one barrier per tile,
//  zero-conflict XOR-swizzle staging/read pair, 2 blocks/CU.)
// GELU=true : transposed acc (mfma(b,a)); sigmoid-GELU + requant -> packed
//             dwords -> pad-132 LDS transpose -> coalesced nt dwordx4 stores.
// GELU=false: fp32 out = acc*s1 + bias, coalesced nt f32 stores.
template <int KDIM, int NDIM, bool GELU>
__global__ void __launch_bounds__(256, 2)
k_gemm(const int8_t* __restrict__ A, const int8_t* __restrict__ B,
       const float* __restrict__ bias, const float* __restrict__ ps1,
       const float* __restrict__ ps2, void* __restrict__ Cout, int Mtiles) {
  constexpr int BM = 128, BN = 128, BKB = 128;
  constexpr int NT = KDIM / BKB;   // 10 (lin1) / 40 (lin2); both even
  constexpr int BNC = NDIM / BN;   // 40 / 10
  constexpr int G = BNC * 4;

  // layout: [A buf0 16K][A buf1 16K][B buf0 16K][B buf1 16K]
  __shared__ __align__(16) int8_t smem[4 * 16384];

  // ---- block mapping: bijective XCD chunk + 4-row grouping (r4-verified) ----
  const int nwg = Mtiles * BNC;
  int bm, bn;
  {
    const int bid = blockIdx.x;
    const int q = nwg >> 3, r = nwg & 7, x = bid & 7, l = bid >> 3;
    const int swz = (x < r ? x * (q + 1) : r * (q + 1) + (x - r) * q) + l;
    if ((Mtiles & 3) == 0) {
      const int g = swz / G, rr = swz % G;
      bn = rr >> 2;
      bm = g * 4 + (rr & 3);
    } else {
      bn = swz % BNC;
      bm = swz / BNC;
    }
  }

  const int tid = threadIdx.x;
  const int lane = tid & 63, wid = tid >> 6;
  const int wr = wid >> 1, wc = wid & 1;  // 2x2 waves, 64x64 out each

  // ---- staging: linear LDS dest, inverse-swizzled global source -------------
  const int srow = tid >> 3;                       // 0..31
  const int soff = (((tid & 7) ^ (srow & 7)) << 4);
  const int8_t* Ath = A + (size_t)(bm * BM + srow) * KDIM + soff;
  const int8_t* Bth = B + (size_t)(bn * BN + srow) * KDIM + soff;
  const int dT = tid * 16;

  auto STAGE = [&](int boff, const int8_t* ga, const int8_t* gb) {
#pragma unroll
    for (int p = 0; p < 4; ++p)
      gload_lds16(ga + (size_t)(p * 32) * KDIM, smem + boff + dT + p * 4096);
#pragma unroll
    for (int p = 0; p < 4; ++p)
      gload_lds16(gb + (size_t)(p * 32) * KDIM,
                  smem + 32768 + boff + dT + p * 4096);
  };

  // ---- fragment addresses (32x32x32: row = lane&31, k = (lane>>5)*16+b) -----
  const int r32 = lane & 31, hi5 = lane >> 5;
  const int fsw = (lane & 7) << 4;   // row&7 == lane&7 (row offsets are mult-8)
  const int kq = hi5 << 4;
  const int8_t* aP[4];
  const int8_t* bP[4];
#pragma unroll
  for (int ks = 0; ks < 4; ++ks) {
    const int koff = (ks * 32 + kq) ^ fsw;
    aP[ks] = smem + (wr * 64 + r32) * BKB + koff;
    bP[ks] = smem + 32768 + (wc * 64 + r32) * BKB + koff;
  }

  i32x16 acc[2][2] = {};

  auto COMPUTE = [&](int boff) {
#pragma unroll
    for (int ks = 0; ks < 4; ++ks) {
      i32x4 a0 = *(const i32x4*)(aP[ks] + boff);
      i32x4 a1 = *(const i32x4*)(aP[ks] + boff + 4096);
      i32x4 b0 = *(const i32x4*)(bP[ks] + boff);
      i32x4 b1 = *(const i32x4*)(bP[ks] + boff + 4096);
      __builtin_amdgcn_s_setprio(1);
      if constexpr (GELU) {  // transposed: acc[n][m], D-row = h, D-col = token
        acc[0][0] = __builtin_amdgcn_mfma_i32_32x32x32_i8(b0, a0, acc[0][0], 0, 0, 0);
        acc[0][1] = __builtin_amdgcn_mfma_i32_32x32x32_i8(b0, a1, acc[0][1], 0, 0, 0);
        acc[1][0] = __builtin_amdgcn_mfma_i32_32x32x32_i8(b1, a0, acc[1][0], 0, 0, 0);
        acc[1][1] = __builtin_amdgcn_mfma_i32_32x32x32_i8(b1, a1, acc[1][1], 0, 0, 0);
      } else {               // normal: acc[m][n], D-row = token, D-col = d
        acc[0][0] = __builtin_amdgcn_mfma_i32_32x32x32_i8(a0, b0, acc[0][0], 0, 0, 0);
        acc[0][1] = __builtin_amdgcn_mfma_i32_32x32x32_i8(a0, b1, acc[0][1], 0, 0, 0);
        acc[1][0] = __builtin_amdgcn_mfma_i32_32x32x32_i8(a1, b0, acc[1][0], 0, 0, 0);
        acc[1][1] = __builtin_amdgcn_mfma_i32_32x32x32_i8(a1, b1, acc[1][1], 0, 0, 0);
      }
      __builtin_amdgcn_s_setprio(0);
    }
  };

  // ---- main loop: unroll-2, static buffer offsets, 1 barrier per tile -------
  STAGE(0, Ath, Bth);
  __syncthreads();
  const int8_t* gA = Ath + BKB;
  const int8_t* gB = Bth + BKB;
#pragma unroll 1
  for (int t = 0; t < NT; t += 2) {
    STAGE(16384, gA, gB);          // tile t+1 -> buf1
    COMPUTE(0);                    // tile t from buf0
    __syncthreads();               // drains vmcnt+lgkm: buf1 ready, buf0 free
    if (t + 2 < NT) STAGE(0, gA + BKB, gB + BKB);  // tile t+2 -> buf0
    COMPUTE(16384);                // tile t+1 from buf1
    __syncthreads();
    gA += 2 * BKB;
    gB += 2 * BKB;
  }

  // ---- epilogue -------------------------------------------------------------
  // 32x32 C/D layout: col = lane&31, row = (reg&3) + 8*(reg>>2) + 4*(lane>>5)
  if constexpr (GELU) {
    const float s1 = *ps1;
    const float rs = 1.0f / (*ps2);
    int8_t* Q = (int8_t*)Cout;
    // pad-132 transpose tile: 128 tok rows x (128 h + 4 pad) B; bank(tok,0)=tok
    int8_t* lb = smem;
#pragma unroll
    for (int n = 0; n < 2; ++n) {
#pragma unroll
      for (int q = 0; q < 4; ++q) {
        const int hl = wc * 64 + n * 32 + q * 8 + hi5 * 4;  // local h base
        const f32x4 bv = *(const f32x4*)(bias + bn * BN + hl);
#pragma unroll
        for (int m = 0; m < 2; ++m) {
          const int tok = wr * 64 + m * 32 + r32;           // local token
          uint32_t pk = 0;
#pragma unroll
          for (int rr = 0; rr < 4; ++rr) {
            const float h = __builtin_fmaf((float)acc[n][m][q * 4 + rr], s1, bv[rr]);
            // sigmoid-GELU: h * sigma(1.702h); exact in both saturation tails
            const float e = __expf(-1.702f * h);
            const float g = h * __builtin_amdgcn_rcpf(1.0f + e);
            float qf = rintf(g * rs);
            qf = fminf(127.0f, fmaxf(-128.0f, qf));
            pk |= ((uint32_t)((int)qf & 255)) << (rr * 8);
          }
          *(uint32_t*)(lb + tok * 132 + hl) = pk;
        }
      }
    }
    __syncthreads();
    // readback: 4-aligned b32 reads (free 2-way max), coalesced nt dwordx4 st
#pragma unroll
    for (int it = 0; it < 4; ++it) {
      const int row = it * 32 + (tid >> 3);
      const int sl = tid & 7;
      const int8_t* rp = lb + row * 132 + sl * 16;
      i32x4 v;
      v.x = *(const int*)(rp);
      v.y = *(const int*)(rp + 4);
      v.z = *(const int*)(rp + 8);
      v.w = *(const int*)(rp + 12);
      __builtin_nontemporal_store(
          v, (i32x4*)(Q + (size_t)(bm * BM + row) * NDIM + bn * BN + sl * 16));
    }
  } else {
    const float s1 = *ps1;
    float* O = (float*)Cout;
    const int colb = bn * BN + wc * 64 + r32;
#pragma unroll
    for (int n = 0; n < 2; ++n) {
      const int col = colb + n * 32;
      const float bv = bias[col];
#pragma unroll
      for (int m = 0; m < 2; ++m) {
        const int rowb = bm * BM + wr * 64 + m * 32 + hi5 * 4;
#pragma unroll
        for (int q = 0; q < 4; ++q)
#pragma unroll
          for (int rr = 0; rr < 4; ++rr) {
            const int row = rowb + q * 8 + rr;
            __builtin_nontemporal_store(
                __builtin_fmaf((float)acc[m][n][q * 4 + rr], s1, bv),
                &O[(size_t)row * NDIM + col]);
          }
      }
    }
  }
}

extern "C" void kernel_launch(void* const* d_in, const int* in_sizes, int n_in,
                              void* d_out, int out_size, void* d_ws, size_t ws_size,
                              hipStream_t stream) {
  (void)in_sizes; (void)n_in; (void)out_size;
  const int*   x32  = (const int*)d_in[0];
  const int*   w132 = (const int*)d_in[1];
  const float* b1   = (const float*)d_in[2];
  const int*   w232 = (const int*)d_in[3];
  const float* b2   = (const float*)d_in[4];
  const float* a1   = (const float*)d_in[5];
  const float* sreq = (const float*)d_in[6];
  const float* a2   = (const float*)d_in[7];
  float* out = (float*)d_out;

  const int M = 4 * 4096;                       // 16384 tokens
  const size_t WN = (size_t)H_DIM * D_DIM;      // 6,553,600 weights each
  constexpr int BM = 128, BN = 128;

  int8_t* w1p  = (int8_t*)d_ws;
  int8_t* w2p  = w1p + WN;
  int8_t* base = w2p + WN;

  // chunk M (multiple of 128) so packed-x chunk + q chunk fit in workspace
  size_t avail = ws_size > 2 * WN ? ws_size - 2 * WN : 0;
  size_t rows = avail / (size_t)(D_DIM + H_DIM);
  int Mc = (int)((rows / BM) * BM);
  if (Mc > M) Mc = M;
  if (Mc < BM) Mc = BM;

  if (Mc == M) {
    // single chunk: fuse w1+w2+x packing into ONE launch
    const long nx = (long)M * D_DIM;
    const long tot = 2 * (long)WN + nx;
    int8_t* xp = base;
    int8_t* q  = base + (size_t)M * D_DIM;
    k_pack3<<<(int)(tot / 4096), 256, 0, stream>>>(w132, w232, x32, w1p,
                                                   (long)WN, nx);
    k_gemm<D_DIM, H_DIM, true><<<(M / BM) * (H_DIM / BN), 256, 0, stream>>>(
        xp, w1p, b1, a1, sreq, q, M / BM);
    k_gemm<H_DIM, D_DIM, false><<<(M / BM) * (D_DIM / BN), 256, 0, stream>>>(
        q, w2p, b2, a2, nullptr, out, M / BM);
    return;
  }

  // fallback: chunked path (small workspace)
  k_pack3<<<(int)(2 * WN / 4096), 256, 0, stream>>>(w132, w232, x32, w1p,
                                                    (long)WN, 0);
  for (int m0 = 0; m0 < M; m0 += Mc) {
    const int mc = (M - m0 < Mc) ? (M - m0) : Mc;
    int8_t* xp = base;
    int8_t* q  = base + (size_t)Mc * D_DIM;
    const size_t nx = (size_t)mc * D_DIM;
    const int mt = mc / BM;
    k_pack<<<(int)(nx / 4096), 256, 0, stream>>>(x32 + (size_t)m0 * D_DIM, xp, (long)nx);
    k_gemm<D_DIM, H_DIM, true><<<mt * (H_DIM / BN), 256, 0, stream>>>(
        xp, w1p, b1, a1, sreq, q, mt);
    k_gemm<H_DIM, D_DIM, false><<<mt * (D_DIM / BN), 256, 0, stream>>>(
        q, w2p, b2, a2, nullptr, out + (size_t)m0 * D_DIM, mt);
  }
}

// Round 13
// 280.405 us; speedup vs baseline: 1.7530x; 1.0608x over previous
//
#include <hip/hip_runtime.h>
#include <stdint.h>
#include <math.h>

typedef __attribute__((ext_vector_type(4))) int i32x4;
typedef __attribute__((ext_vector_type(16))) int i32x16;
typedef __attribute__((ext_vector_type(4))) float f32x4;

constexpr int D_DIM = 1280;   // embedding dim (lin1 K, lin2 N)
constexpr int H_DIM = 5120;   // mlp dim      (lin1 N, lin2 K)

__device__ __forceinline__ void gload_lds16(const void* g, void* l) {
  __builtin_amdgcn_global_load_lds(
      (const __attribute__((address_space(1))) void*)g,
      (__attribute__((address_space(3))) void*)l,
      16, 0, 0);
}

__device__ __forceinline__ i32x4 pack16(const int* __restrict__ p) {
  i32x4 a = *(const i32x4*)(p);
  i32x4 b = *(const i32x4*)(p + 4);
  i32x4 c = *(const i32x4*)(p + 8);
  i32x4 d = *(const i32x4*)(p + 12);
  i32x4 r;
  r.x = (a.x & 255) | ((a.y & 255) << 8) | ((a.z & 255) << 16) | (a.w << 24);
  r.y = (b.x & 255) | ((b.y & 255) << 8) | ((b.z & 255) << 16) | (b.w << 24);
  r.z = (c.x & 255) | ((c.y & 255) << 8) | ((c.z & 255) << 16) | (c.w << 24);
  r.w = (d.x & 255) | ((d.y & 255) << 8) | ((d.z & 255) << 16) | (d.w << 24);
  return r;
}

// ---- fused pack: w1 | w2 | x in ONE launch (int32 sign-extended -> int8) ----
__global__ void __launch_bounds__(256) k_pack3(const int* __restrict__ s1,
                                               const int* __restrict__ s2,
                                               const int* __restrict__ s3,
                                               int8_t* __restrict__ out,
                                               long wn, long nx) {
  long i = ((long)blockIdx.x * 256 + threadIdx.x) * 16;
  if (i >= 2 * wn + nx) return;
  const int* p = (i < wn) ? (s1 + i)
               : (i < 2 * wn) ? (s2 + (i - wn)) : (s3 + (i - 2 * wn));
  *(i32x4*)(out + i) = pack16(p);
}

__global__ void __launch_bounds__(256) k_pack(const int* __restrict__ in,
                                              int8_t* __restrict__ out,
                                              long n) {
  long i = ((long)blockIdx.x * 256 + threadIdx.x) * 16;
  if (i >= n) return;
  *(i32x4*)(out + i) = pack16(in + i);
}

// ---- fused int8 GEMM: 128x128 tile, BK=128, 32x32x32 MFMA, static dbuf ------
// (r9-verified structure: simple 2-phase dbuf, one barrier per tile,
//  zero-conflict XOR-swizzle staging/read pair, 2 blocks/CU.)
// GELU=true : transposed acc (mfma(b,a)); sigmoid-GELU + requant -> packed
//             dwords -> pad-132 LDS transpose -> coalesced dwordx4 stores
//             (REGULAR stores: Q is lin2's input, keep it in L2/L3).
// GELU=false: fp32 out = acc*s1 + bias, coalesced NT f32 stores (never re-read).
template <int KDIM, int NDIM, bool GELU>
__global__ void __launch_bounds__(256, 2)
k_gemm(const int8_t* __restrict__ A, const int8_t* __restrict__ B,
       const float* __restrict__ bias, const float* __restrict__ ps1,
       const float* __restrict__ ps2, void* __restrict__ Cout, int Mtiles) {
  constexpr int BM = 128, BN = 128, BKB = 128;
  constexpr int NT = KDIM / BKB;   // 10 (lin1) / 40 (lin2); both even
  constexpr int BNC = NDIM / BN;   // 40 / 10
  constexpr int G = BNC * 4;

  // layout: [A buf0 16K][A buf1 16K][B buf0 16K][B buf1 16K]
  __shared__ __align__(16) int8_t smem[4 * 16384];

  // ---- block mapping: bijective XCD chunk + 4-row grouping (r4-verified) ----
  const int nwg = Mtiles * BNC;
  int bm, bn;
  {
    const int bid = blockIdx.x;
    const int q = nwg >> 3, r = nwg & 7, x = bid & 7, l = bid >> 3;
    const int swz = (x < r ? x * (q + 1) : r * (q + 1) + (x - r) * q) + l;
    if ((Mtiles & 3) == 0) {
      const int g = swz / G, rr = swz % G;
      bn = rr >> 2;
      bm = g * 4 + (rr & 3);
    } else {
      bn = swz % BNC;
      bm = swz / BNC;
    }
  }

  const int tid = threadIdx.x;
  const int lane = tid & 63, wid = tid >> 6;
  const int wr = wid >> 1, wc = wid & 1;  // 2x2 waves, 64x64 out each

  // ---- staging: linear LDS dest, inverse-swizzled global source -------------
  const int srow = tid >> 3;                       // 0..31
  const int soff = (((tid & 7) ^ (srow & 7)) << 4);
  const int8_t* Ath = A + (size_t)(bm * BM + srow) * KDIM + soff;
  const int8_t* Bth = B + (size_t)(bn * BN + srow) * KDIM + soff;
  const int dT = tid * 16;

  auto STAGE = [&](int boff, const int8_t* ga, const int8_t* gb) {
#pragma unroll
    for (int p = 0; p < 4; ++p)
      gload_lds16(ga + (size_t)(p * 32) * KDIM, smem + boff + dT + p * 4096);
#pragma unroll
    for (int p = 0; p < 4; ++p)
      gload_lds16(gb + (size_t)(p * 32) * KDIM,
                  smem + 32768 + boff + dT + p * 4096);
  };

  // ---- fragment addresses (32x32x32: row = lane&31, k = (lane>>5)*16+b) -----
  const int r32 = lane & 31, hi5 = lane >> 5;
  const int fsw = (lane & 7) << 4;   // row&7 == lane&7 (row offsets are mult-8)
  const int kq = hi5 << 4;
  const int8_t* aP[4];
  const int8_t* bP[4];
#pragma unroll
  for (int ks = 0; ks < 4; ++ks) {
    const int koff = (ks * 32 + kq) ^ fsw;
    aP[ks] = smem + (wr * 64 + r32) * BKB + koff;
    bP[ks] = smem + 32768 + (wc * 64 + r32) * BKB + koff;
  }

  i32x16 acc[2][2] = {};

  auto COMPUTE = [&](int boff) {
#pragma unroll
    for (int ks = 0; ks < 4; ++ks) {
      i32x4 a0 = *(const i32x4*)(aP[ks] + boff);
      i32x4 a1 = *(const i32x4*)(aP[ks] + boff + 4096);
      i32x4 b0 = *(const i32x4*)(bP[ks] + boff);
      i32x4 b1 = *(const i32x4*)(bP[ks] + boff + 4096);
      __builtin_amdgcn_s_setprio(1);
      if constexpr (GELU) {  // transposed: acc[n][m], D-row = h, D-col = token
        acc[0][0] = __builtin_amdgcn_mfma_i32_32x32x32_i8(b0, a0, acc[0][0], 0, 0, 0);
        acc[0][1] = __builtin_amdgcn_mfma_i32_32x32x32_i8(b0, a1, acc[0][1], 0, 0, 0);
        acc[1][0] = __builtin_amdgcn_mfma_i32_32x32x32_i8(b1, a0, acc[1][0], 0, 0, 0);
        acc[1][1] = __builtin_amdgcn_mfma_i32_32x32x32_i8(b1, a1, acc[1][1], 0, 0, 0);
      } else {               // normal: acc[m][n], D-row = token, D-col = d
        acc[0][0] = __builtin_amdgcn_mfma_i32_32x32x32_i8(a0, b0, acc[0][0], 0, 0, 0);
        acc[0][1] = __builtin_amdgcn_mfma_i32_32x32x32_i8(a0, b1, acc[0][1], 0, 0, 0);
        acc[1][0] = __builtin_amdgcn_mfma_i32_32x32x32_i8(a1, b0, acc[1][0], 0, 0, 0);
        acc[1][1] = __builtin_amdgcn_mfma_i32_32x32x32_i8(a1, b1, acc[1][1], 0, 0, 0);
      }
      __builtin_amdgcn_s_setprio(0);
    }
  };

  // ---- main loop: unroll-2, static buffer offsets, 1 barrier per tile -------
  STAGE(0, Ath, Bth);
  __syncthreads();
  const int8_t* gA = Ath + BKB;
  const int8_t* gB = Bth + BKB;
#pragma unroll 1
  for (int t = 0; t < NT; t += 2) {
    STAGE(16384, gA, gB);          // tile t+1 -> buf1
    COMPUTE(0);                    // tile t from buf0
    __syncthreads();               // drains vmcnt+lgkm: buf1 ready, buf0 free
    if (t + 2 < NT) STAGE(0, gA + BKB, gB + BKB);  // tile t+2 -> buf0
    COMPUTE(16384);                // tile t+1 from buf1
    __syncthreads();
    gA += 2 * BKB;
    gB += 2 * BKB;
  }

  // ---- epilogue -------------------------------------------------------------
  // 32x32 C/D layout: col = lane&31, row = (reg&3) + 8*(reg>>2) + 4*(lane>>5)
  if constexpr (GELU) {
    const float s1 = *ps1;
    const float rs = 1.0f / (*ps2);
    int8_t* Q = (int8_t*)Cout;
    // pad-132 transpose tile: 128 tok rows x (128 h + 4 pad) B; bank(tok,0)=tok
    int8_t* lb = smem;
#pragma unroll
    for (int n = 0; n < 2; ++n) {
#pragma unroll
      for (int q = 0; q < 4; ++q) {
        const int hl = wc * 64 + n * 32 + q * 8 + hi5 * 4;  // local h base
        const f32x4 bv = *(const f32x4*)(bias + bn * BN + hl);
#pragma unroll
        for (int m = 0; m < 2; ++m) {
          const int tok = wr * 64 + m * 32 + r32;           // local token
          uint32_t pk = 0;
#pragma unroll
          for (int rr = 0; rr < 4; ++rr) {
            const float h = __builtin_fmaf((float)acc[n][m][q * 4 + rr], s1, bv[rr]);
            // sigmoid-GELU: h * sigma(1.702h); exact in both saturation tails
            const float e = __expf(-1.702f * h);
            const float g = h * __builtin_amdgcn_rcpf(1.0f + e);
            float qf = rintf(g * rs);
            qf = fminf(127.0f, fmaxf(-128.0f, qf));
            pk |= ((uint32_t)((int)qf & 255)) << (rr * 8);
          }
          *(uint32_t*)(lb + tok * 132 + hl) = pk;
        }
      }
    }
    __syncthreads();
    // readback: 4-aligned b32 reads (free 2-way max), coalesced dwordx4 stores
#pragma unroll
    for (int it = 0; it < 4; ++it) {
      const int row = it * 32 + (tid >> 3);
      const int sl = tid & 7;
      const int8_t* rp = lb + row * 132 + sl * 16;
      i32x4 v;
      v.x = *(const int*)(rp);
      v.y = *(const int*)(rp + 4);
      v.z = *(const int*)(rp + 8);
      v.w = *(const int*)(rp + 12);
      *(i32x4*)(Q + (size_t)(bm * BM + row) * NDIM + bn * BN + sl * 16) = v;
    }
  } else {
    const float s1 = *ps1;
    float* O = (float*)Cout;
    const int colb = bn * BN + wc * 64 + r32;
#pragma unroll
    for (int n = 0; n < 2; ++n) {
      const int col = colb + n * 32;
      const float bv = bias[col];
#pragma unroll
      for (int m = 0; m < 2; ++m) {
        const int rowb = bm * BM + wr * 64 + m * 32 + hi5 * 4;
#pragma unroll
        for (int q = 0; q < 4; ++q)
#pragma unroll
          for (int rr = 0; rr < 4; ++rr) {
            const int row = rowb + q * 8 + rr;
            __builtin_nontemporal_store(
                __builtin_fmaf((float)acc[m][n][q * 4 + rr], s1, bv),
                &O[(size_t)row * NDIM + col]);
          }
      }
    }
  }
}

extern "C" void kernel_launch(void* const* d_in, const int* in_sizes, int n_in,
                              void* d_out, int out_size, void* d_ws, size_t ws_size,
                              hipStream_t stream) {
  (void)in_sizes; (void)n_in; (void)out_size;
  const int*   x32  = (const int*)d_in[0];
  const int*   w132 = (const int*)d_in[1];
  const float* b1   = (const float*)d_in[2];
  const int*   w232 = (const int*)d_in[3];
  const float* b2   = (const float*)d_in[4];
  const float* a1   = (const float*)d_in[5];
  const float* sreq = (const float*)d_in[6];
  const float* a2   = (const float*)d_in[7];
  float* out = (float*)d_out;

  const int M = 4 * 4096;                       // 16384 tokens
  const size_t WN = (size_t)H_DIM * D_DIM;      // 6,553,600 weights each
  constexpr int BM = 128, BN = 128;

  int8_t* w1p  = (int8_t*)d_ws;
  int8_t* w2p  = w1p + WN;
  int8_t* base = w2p + WN;

  // chunk M (multiple of 128) so packed-x chunk + q chunk fit in workspace
  size_t avail = ws_size > 2 * WN ? ws_size - 2 * WN : 0;
  size_t rows = avail / (size_t)(D_DIM + H_DIM);
  int Mc = (int)((rows / BM) * BM);
  if (Mc > M) Mc = M;
  if (Mc < BM) Mc = BM;

  if (Mc == M) {
    // single chunk: fuse w1+w2+x packing into ONE launch
    const long nx = (long)M * D_DIM;
    const long tot = 2 * (long)WN + nx;
    int8_t* xp = base;
    int8_t* q  = base + (size_t)M * D_DIM;
    k_pack3<<<(int)(tot / 4096), 256, 0, stream>>>(w132, w232, x32, w1p,
                                                   (long)WN, nx);
    k_gemm<D_DIM, H_DIM, true><<<(M / BM) * (H_DIM / BN), 256, 0, stream>>>(
        xp, w1p, b1, a1, sreq, q, M / BM);
    k_gemm<H_DIM, D_DIM, false><<<(M / BM) * (D_DIM / BN), 256, 0, stream>>>(
        q, w2p, b2, a2, nullptr, out, M / BM);
    return;
  }

  // fallback: chunked path (small workspace)
  k_pack3<<<(int)(2 * WN / 4096), 256, 0, stream>>>(w132, w232, x32, w1p,
                                                    (long)WN, 0);
  for (int m0 = 0; m0 < M; m0 += Mc) {
    const int mc = (M - m0 < Mc) ? (M - m0) : Mc;
    int8_t* xp = base;
    int8_t* q  = base + (size_t)Mc * D_DIM;
    const size_t nx = (size_t)mc * D_DIM;
    const int mt = mc / BM;
    k_pack<<<(int)(nx / 4096), 256, 0, stream>>>(x32 + (size_t)m0 * D_DIM, xp, (long)nx);
    k_gemm<D_DIM, H_DIM, true><<<mt * (H_DIM / BN), 256, 0, stream>>>(
        xp, w1p, b1, a1, sreq, q, mt);
    k_gemm<H_DIM, D_DIM, false><<<mt * (D_DIM / BN), 256, 0, stream>>>(
        q, w2p, b2, a2, nullptr, out + (size_t)m0 * D_DIM, mt);
  }
}